// Round 1
// baseline (261.573 us; speedup 1.0000x reference)
//
#include <hip/hip_runtime.h>
#include <math.h>

#define IMG 256
#define NA  360
#define ND  363
#define NB  2          // B*C rows of images
#define KMAX ((ND - 1) / 2)   // 181

// ---------------------------------------------------------------------------
// Kernel 1: ramp-filter impulse response h[n] = (4/D^2) * sum_{k=1}^{181} k*cos(2pi k n / D)
// (exact real form of ifft(filt) for filt[k] = 2*min(k,D-k)/D, filt[0]=0)
// One block; f64 accumulation — 363*181 f64 ops, negligible.
// ---------------------------------------------------------------------------
__global__ void fbp_compute_h(float* __restrict__ h) {
    int n = blockIdx.x * blockDim.x + threadIdx.x;
    if (n >= ND) return;
    double w = 2.0 * M_PI * (double)n / (double)ND;
    double acc = 0.0;
    for (int k = 1; k <= KMAX; ++k) {
        acc += (double)k * cos(w * (double)k);
    }
    h[n] = (float)(acc * 4.0 / ((double)ND * (double)ND));
}

// ---------------------------------------------------------------------------
// Kernel 2: circular convolution per sinogram row.
// filtered[r][d] = sum_m sino[r][m] * h[(d-m) mod D]
// One block per row (720 blocks). Row + h staged in LDS.
// Inner loop: s_row[m] is a wave broadcast (free); s_h[d-m] is stride-1
// across lanes (2 lanes/bank = free on gfx950).
// ---------------------------------------------------------------------------
__global__ __launch_bounds__(384) void fbp_conv(const float* __restrict__ sino,
                                                const float* __restrict__ h,
                                                float* __restrict__ filt) {
    __shared__ float s_row[ND];
    __shared__ float s_h[ND];
    const int row = blockIdx.x;
    const int t = threadIdx.x;
    const float* src = sino + (size_t)row * ND;
    if (t < ND) {
        s_row[t] = src[t];
        s_h[t]   = h[t];
    }
    __syncthreads();
    if (t < ND) {
        const int d = t;
        float acc = 0.f;
#pragma unroll 4
        for (int m = 0; m < ND; ++m) {
            int idx = d - m;
            if (idx < 0) idx += ND;
            acc = fmaf(s_row[m], s_h[idx], acc);
        }
        filt[(size_t)row * ND + d] = acc;
    }
}

// ---------------------------------------------------------------------------
// Kernel 3: backprojection. One thread per output pixel, loop over 360 angles.
// u = x*cos(a)*K + y*sin(a)*K + U0 ; bilinear sample with zero padding.
// cos/sin tables (pre-scaled by K) built in LDS per block.
// filtered array is ~1 MB -> L2-resident; consecutive lanes step u by
// ~1.4*cos(a) -> good spatial locality.
// ---------------------------------------------------------------------------
__global__ __launch_bounds__(256) void fbp_backproj(const float* __restrict__ filt,
                                                    float* __restrict__ out,
                                                    float K, float U0) {
    __shared__ float cK[NA];
    __shared__ float sK[NA];
    const int t = threadIdx.x;
    for (int a = t; a < NA; a += 256) {
        float ang = (float)M_PI * (float)a / (float)NA;
        float s, c;
        sincosf(ang, &s, &c);
        cK[a] = c * K;
        sK[a] = s * K;
    }
    __syncthreads();

    const int gid = blockIdx.x * 256 + t;        // [0, NB*IMG*IMG)
    const int b   = gid >> 16;                   // / (256*256)
    const int pix = gid & 65535;
    const int iy  = pix >> 8;
    const int jx  = pix & 255;
    const float xg = -1.f + 2.f * (float)jx / (float)(IMG - 1);
    const float yg = -1.f + 2.f * (float)iy / (float)(IMG - 1);

    const float* base = filt + (size_t)b * NA * ND;
    float acc = 0.f;
    for (int a = 0; a < NA; ++a) {
        float u  = fmaf(xg, cK[a], fmaf(yg, sK[a], U0));
        float uf = floorf(u);
        int   i0 = (int)uf;
        float w1 = u - uf;
        const float* rowp = base + a * ND;
        float v = 0.f;
        if (i0 >= 0 && i0 < ND)          v  = (1.f - w1) * rowp[i0];
        if (i0 + 1 >= 0 && i0 + 1 < ND)  v  = fmaf(w1, rowp[i0 + 1], v);
        acc += v;
    }
    out[gid] = acc * ((float)M_PI / (float)NA);
}

// ---------------------------------------------------------------------------
extern "C" void kernel_launch(void* const* d_in, const int* in_sizes, int n_in,
                              void* d_out, int out_size, void* d_ws, size_t ws_size,
                              hipStream_t stream) {
    const float* sino = (const float*)d_in[0];   // (2,1,360,363) f32
    float* out = (float*)d_out;                  // (2,1,256,256) f32

    // workspace layout: h (363 floats, padded to 512) | filtered (720*363 floats)
    float* h    = (float*)d_ws;
    float* filt = (float*)d_ws + 512;

    // geometry constants (match reference exactly, computed in double)
    const double scale = (double)(IMG - 1) / 2.0 * sqrt(2.0) / ((double)(ND - 1) / 2.0);
    const float  K  = (float)(0.5 * (double)(ND - 1) / scale);
    const float  U0 = 0.5f * (float)(ND - 1);

    fbp_compute_h<<<1, 384, 0, stream>>>(h);
    fbp_conv<<<NB * NA, 384, 0, stream>>>(sino, h, filt);
    fbp_backproj<<<NB * IMG * IMG / 256, 256, 0, stream>>>(filt, out, K, U0);
}

// Round 2
// 98.148 us; speedup vs baseline: 2.6651x; 2.6651x over previous
//
#include <hip/hip_runtime.h>
#include <math.h>

#define IMG 256
#define NA  360
#define ND  363
#define NB  2                  // B*C image count
#define KMAX 181               // (ND-1)/2
#define ST  544                // padded row stride for filtered sinogram
#define PAD 76                 // left zero-pad (min u = 181 - 181.7*sqrt(2) > -76)
// reachable padded index range: [0, 514] < ST  (i0 in [-76,437], i1 <= 438)

// ---------------------------------------------------------------------------
// Kernel 1: ramp filter (circular conv) + zero-padded output layout.
// h table built per-block from the closed form of sum_{k=1}^{K} k*cos(kw):
//   S(w) = ((K+1)cos(Kw) - K*cos((K+1)w) - 1) / (2*(1-cos w)),  S(0)=K(K+1)/2
//   h[n] = S(2*pi*n/ND) * 4/ND^2
// Conv loop iterates m DOWNWARD so the LDS table index ascends: lanes read
// consecutive addresses (conflict-free), sinogram tap is wave-uniform (SMEM).
// ---------------------------------------------------------------------------
__global__ __launch_bounds__(384) void fbp_conv(const float* __restrict__ sino,
                                                float* __restrict__ filt) {
    __shared__ float ht[2 * ND - 1];   // ht[i] = h_circ[i - 362], i in [0,725)
    const int row = blockIdx.x;
    const int t = threadIdx.x;

    for (int i = t; i < 2 * ND - 1; i += 384) {
        int n = i - (ND - 1);
        double S;
        if (n == 0) {
            S = (double)KMAX * (double)(KMAX + 1) * 0.5;   // 16471
        } else {
            double w = (2.0 * M_PI / (double)ND) * (double)n;
            S = ((double)(KMAX + 1) * cos((double)KMAX * w)
               - (double)KMAX * cos((double)(KMAX + 1) * w) - 1.0)
              / (2.0 * (1.0 - cos(w)));
        }
        ht[i] = (float)(S * (4.0 / ((double)ND * (double)ND)));
    }
    __syncthreads();

    const float* __restrict__ srow = sino + (size_t)row * ND;
    float* __restrict__ orow = filt + (size_t)row * ST;

    if (t < ND) {
        float acc = 0.f;
#pragma unroll 4
        for (int m = ND - 1; m >= 0; --m) {
            // srow[m] is wave-uniform (scalar load path); ht index ascends with
            // iteration: lanes stride-1 in LDS -> conflict-free.
            acc = fmaf(srow[m], ht[t + (ND - 1) - m], acc);
        }
        orow[PAD + t] = acc;
    }
    // zero pads: [0,PAD) and [PAD+ND, ST)
    if (t < PAD) orow[t] = 0.f;
    if (t >= PAD && t < PAD + (ST - PAD - ND)) orow[PAD + ND + (t - PAD)] = 0.f;
}

// ---------------------------------------------------------------------------
// Kernel 2: backprojection, latency-optimized.
//  - 8-way angle split (45 angles/block) for occupancy: 2048 blocks = 8/CU.
//  - 2 pixels/thread (rows iy and iy+128): shares the angle table read and
//    doubles independent load chains (ILP).
//  - zero-padded filt rows -> unconditional loads, no exec-mask branches.
//  - partial sums combined with atomicAdd into zeroed d_out.
// ---------------------------------------------------------------------------
__global__ __launch_bounds__(256) void fbp_backproj(const float* __restrict__ filt,
                                                    float* __restrict__ out,
                                                    float K, float U0p) {
    __shared__ float2 tab[NA];         // (cos*K, sin*K)
    const int t = threadIdx.x;
    for (int a = t; a < NA; a += 256) {
        float ang = (float)M_PI * (float)a / (float)NA;
        float s, c;
        sincosf(ang, &s, &c);
        tab[a] = make_float2(c * K, s * K);
    }
    __syncthreads();

    const int blk   = blockIdx.x;
    const int chunk = blk >> 8;                 // [0,8) angle chunk
    const int pb    = blk & 255;                // pixel block
    const int gid   = pb * 256 + t;             // [0, 65536)
    const int img   = gid >> 15;                // {0,1}
    const int rest  = gid & 32767;
    const int iy    = rest >> 8;                // [0,128)
    const int jx    = rest & 255;

    const float xg = -1.f + 2.f * (float)jx / 255.f;
    const float yg = -1.f + 2.f * (float)iy / 255.f;
    const float DY = 2.f * 128.f / 255.f;       // y offset of second pixel

    const float* __restrict__ base = filt + (size_t)img * NA * ST;
    float acc0 = 0.f, acc1 = 0.f;
    const int a0 = chunk * (NA / 8);            // 45 angles per chunk

#pragma unroll 5
    for (int a = a0; a < a0 + NA / 8; ++a) {
        float2 cs = tab[a];
        float u0 = fmaf(xg, cs.x, fmaf(yg, cs.y, U0p));
        float u1 = fmaf(DY, cs.y, u0);
        float f0 = floorf(u0);
        float f1 = floorf(u1);
        int   i0 = (int)f0;
        int   i1 = (int)f1;
        float w0 = u0 - f0;
        float w1 = u1 - f1;
        const float* rp = base + a * ST;
        float v0 = (1.f - w0) * rp[i0];
        v0 = fmaf(w0, rp[i0 + 1], v0);
        float v1 = (1.f - w1) * rp[i1];
        v1 = fmaf(w1, rp[i1 + 1], v1);
        acc0 += v0;
        acc1 += v1;
    }

    const float SCL = (float)M_PI / (float)NA;
    const int p0 = img * 65536 + iy * 256 + jx;
    atomicAdd(out + p0,                 acc0 * SCL);
    atomicAdd(out + p0 + 128 * 256,     acc1 * SCL);
}

// ---------------------------------------------------------------------------
extern "C" void kernel_launch(void* const* d_in, const int* in_sizes, int n_in,
                              void* d_out, int out_size, void* d_ws, size_t ws_size,
                              hipStream_t stream) {
    const float* sino = (const float*)d_in[0];   // (2,1,360,363) f32
    float* out = (float*)d_out;                  // (2,1,256,256) f32
    float* filt = (float*)d_ws;                  // 720 * 544 floats = 1.57 MB

    // geometry constants (double, matches reference)
    const double scale = (double)(IMG - 1) / 2.0 * sqrt(2.0) / ((double)(ND - 1) / 2.0);
    const float  K   = (float)(0.5 * (double)(ND - 1) / scale);
    const float  U0p = 0.5f * (float)(ND - 1) + (float)PAD;

    fbp_conv<<<NB * NA, 384, 0, stream>>>(sino, filt);
    hipMemsetAsync(d_out, 0, (size_t)out_size * sizeof(float), stream);
    fbp_backproj<<<8 * 256, 256, 0, stream>>>(filt, out, K, U0p);
}

// Round 3
// 97.358 us; speedup vs baseline: 2.6867x; 1.0081x over previous
//
#include <hip/hip_runtime.h>
#include <math.h>

#define IMG 256
#define NA  360
#define ND  363
#define NB  2                  // B*C image count
#define KMAX 181               // (ND-1)/2
#define ST  544                // padded row stride for filtered sinogram
#define PAD 76                 // left zero-pad (min u = 181 - 181.7*sqrt(2) > -76)
// reachable padded index range: [0, 514] < ST  (i0 in [-76,437], i1 <= 438)

// ---------------------------------------------------------------------------
// Kernel 1: ramp filter (circular conv) + zero-padded output layout.
// h table per block from the closed form of sum_{k=1}^{K} k*cos(kw):
//   S(w) = ((K+1)cos(Kw) - K*cos((K+1)w) - 1) / (2*(1-cos w)),  S(0)=K(K+1)/2
//   h[n] = S(2*pi*n/ND) * 4/ND^2
// Conv loop iterates m DOWNWARD so the LDS table index ascends: lanes read
// consecutive addresses (conflict-free), sinogram tap is wave-uniform (SMEM).
// ---------------------------------------------------------------------------
__global__ __launch_bounds__(384) void fbp_conv(const float* __restrict__ sino,
                                                float* __restrict__ filt) {
    __shared__ float ht[2 * ND - 1];   // ht[i] = h_circ[i - 362], i in [0,725)
    const int row = blockIdx.x;
    const int t = threadIdx.x;

    for (int i = t; i < 2 * ND - 1; i += 384) {
        int n = i - (ND - 1);
        double S;
        if (n == 0) {
            S = (double)KMAX * (double)(KMAX + 1) * 0.5;   // 16471
        } else {
            double w = (2.0 * M_PI / (double)ND) * (double)n;
            S = ((double)(KMAX + 1) * cos((double)KMAX * w)
               - (double)KMAX * cos((double)(KMAX + 1) * w) - 1.0)
              / (2.0 * (1.0 - cos(w)));
        }
        ht[i] = (float)(S * (4.0 / ((double)ND * (double)ND)));
    }
    __syncthreads();

    const float* __restrict__ srow = sino + (size_t)row * ND;
    float* __restrict__ orow = filt + (size_t)row * ST;

    if (t < ND) {
        float acc = 0.f;
#pragma unroll 4
        for (int m = ND - 1; m >= 0; --m) {
            // srow[m] wave-uniform (scalar path); ht index ascends with
            // iteration: lanes stride-1 in LDS -> conflict-free.
            acc = fmaf(srow[m], ht[t + (ND - 1) - m], acc);
        }
        orow[PAD + t] = acc;
    }
    // zero pads: [0,PAD) and [PAD+ND, ST)
    if (t < PAD) orow[t] = 0.f;
    if (t >= PAD && t < PAD + (ST - PAD - ND)) orow[PAD + ND + (t - PAD)] = 0.f;
}

// ---------------------------------------------------------------------------
// Kernel 2: backprojection with INTRA-BLOCK angle split (no atomics/memset).
//  - 2048 blocks x 256 threads: block covers 64 consecutive pixels of one
//    image row; wave w (= t>>6) handles angles [w*90, w*90+90).
//  - zero-padded filt rows -> unconditional branchless loads.
//  - 4 partials combined through LDS, one coalesced 64-wide store.
//  - __launch_bounds__(256,8): 8 waves/EU -> 8 blocks/CU (100% occupancy),
//    enough TLP to hide the ~200cyc L2 gather latency.
// ---------------------------------------------------------------------------
__global__ __launch_bounds__(256, 8) void fbp_backproj(const float* __restrict__ filt,
                                                       float* __restrict__ out,
                                                       float K, float U0p) {
    __shared__ float2 tab[NA];         // (cos*K, sin*K)
    __shared__ float  part[256];
    const int t = threadIdx.x;
    for (int a = t; a < NA; a += 256) {
        float ang = (float)M_PI * (float)a / (float)NA;
        float s, c;
        sincosf(ang, &s, &c);
        tab[a] = make_float2(c * K, s * K);
    }
    __syncthreads();

    const int blk  = blockIdx.x;             // [0, 2048)
    const int img  = blk >> 10;              // {0,1}
    const int iy   = (blk >> 2) & 255;       // [0,256)
    const int jx0  = (blk & 3) * 64;         // pixel segment base
    const int lane = t & 63;                 // pixel within segment
    const int wv   = t >> 6;                 // angle chunk [0,4)

    const float xg = -1.f + 2.f * (float)(jx0 + lane) / 255.f;
    const float yg = -1.f + 2.f * (float)iy / 255.f;

    const float* __restrict__ base = filt + (size_t)img * NA * ST;
    float acc = 0.f;
    const int a0 = wv * (NA / 4);            // 90 angles per wave

#pragma unroll 6
    for (int a = a0; a < a0 + NA / 4; ++a) {
        float2 cs = tab[a];
        float u  = fmaf(xg, cs.x, fmaf(yg, cs.y, U0p));
        float uf = floorf(u);
        int   i0 = (int)uf;
        float w1 = u - uf;
        const float* rp = base + a * ST;
        float v = (1.f - w1) * rp[i0];
        acc += fmaf(w1, rp[i0 + 1], v);
    }

    part[t] = acc;
    __syncthreads();

    if (t < 64) {
        float s = part[t] + part[t + 64] + part[t + 128] + part[t + 192];
        out[img * 65536 + iy * 256 + jx0 + t] = s * ((float)M_PI / (float)NA);
    }
}

// ---------------------------------------------------------------------------
extern "C" void kernel_launch(void* const* d_in, const int* in_sizes, int n_in,
                              void* d_out, int out_size, void* d_ws, size_t ws_size,
                              hipStream_t stream) {
    const float* sino = (const float*)d_in[0];   // (2,1,360,363) f32
    float* out = (float*)d_out;                  // (2,1,256,256) f32
    float* filt = (float*)d_ws;                  // 720 * 544 floats = 1.57 MB

    // geometry constants (double, matches reference)
    const double scale = (double)(IMG - 1) / 2.0 * sqrt(2.0) / ((double)(ND - 1) / 2.0);
    const float  K   = (float)(0.5 * (double)(ND - 1) / scale);
    const float  U0p = 0.5f * (float)(ND - 1) + (float)PAD;

    fbp_conv<<<NB * NA, 384, 0, stream>>>(sino, filt);
    fbp_backproj<<<2048, 256, 0, stream>>>(filt, out, K, U0p);
}

// Round 4
// 95.691 us; speedup vs baseline: 2.7335x; 1.0174x over previous
//
#include <hip/hip_runtime.h>
#include <math.h>

#define IMG 256
#define NA  360
#define ND  363
#define NB  2                  // B*C image count
#define KMAX 181               // (ND-1)/2
#define ST  544                // padded row stride for filtered sinogram
#define PAD 76                 // left zero-pad (min u = 181 - 181.7*sqrt(2) > -76)
// reachable padded index range: [0, 514] < ST  (i0 in [-76,437], i1 <= 438)

// ---------------------------------------------------------------------------
// Kernel 1: ramp filter (circular conv) + zero-padded output layout.
// h table per block from the closed form of sum_{k=1}^{K} k*cos(kw):
//   S(w) = ((K+1)cos(Kw) - K*cos((K+1)w) - 1) / (2*(1-cos w)),  S(0)=K(K+1)/2
//   h[n] = S(2*pi*n/ND) * 4/ND^2
// Conv loop iterates m DOWNWARD so the LDS table index ascends: lanes read
// consecutive addresses (conflict-free), sinogram tap is wave-uniform (SMEM).
// LDS-pipe bound at ~5-6 us (379 MB of LDS tap traffic / 78 TB/s).
// ---------------------------------------------------------------------------
__global__ __launch_bounds__(384) void fbp_conv(const float* __restrict__ sino,
                                                float* __restrict__ filt) {
    __shared__ float ht[2 * ND - 1];   // ht[i] = h_circ[i - 362], i in [0,725)
    const int row = blockIdx.x;
    const int t = threadIdx.x;

    for (int i = t; i < 2 * ND - 1; i += 384) {
        int n = i - (ND - 1);
        double S;
        if (n == 0) {
            S = (double)KMAX * (double)(KMAX + 1) * 0.5;   // 16471
        } else {
            double w = (2.0 * M_PI / (double)ND) * (double)n;
            S = ((double)(KMAX + 1) * cos((double)KMAX * w)
               - (double)KMAX * cos((double)(KMAX + 1) * w) - 1.0)
              / (2.0 * (1.0 - cos(w)));
        }
        ht[i] = (float)(S * (4.0 / ((double)ND * (double)ND)));
    }
    __syncthreads();

    const float* __restrict__ srow = sino + (size_t)row * ND;
    float* __restrict__ orow = filt + (size_t)row * ST;

    if (t < ND) {
        float acc = 0.f;
#pragma unroll 4
        for (int m = ND - 1; m >= 0; --m) {
            // srow[m] wave-uniform (scalar path); ht index ascends with
            // iteration: lanes stride-1 in LDS -> conflict-free.
            acc = fmaf(srow[m], ht[t + (ND - 1) - m], acc);
        }
        orow[PAD + t] = acc;
    }
    // zero pads: [0,PAD) and [PAD+ND, ST)
    if (t < PAD) orow[t] = 0.f;
    if (t >= PAD && t < PAD + (ST - PAD - ND)) orow[PAD + ND + (t - PAD)] = 0.f;
}

// ---------------------------------------------------------------------------
// Kernel 2: backprojection.
//  - 2048 blocks x 256 threads: block covers 64 consecutive pixels of one
//    image row; wave w (= t>>6) handles angles [w*90, w*90+90).
//  - zero-padded filt rows -> unconditional branchless loads; both bilinear
//    taps fetched with ONE float2 gather (global_load_dwordx2; gfx950
//    handles the 4B-aligned case) -> half the VMEM/TA work vs 2 loads.
//  - fused lerp: acc = fma(w, B-A, acc+A)  (~8 VALU/angle).
//  - 4 wave-partials combined in LDS, one coalesced 64-wide store.
// ---------------------------------------------------------------------------
__global__ __launch_bounds__(256, 8) void fbp_backproj(const float* __restrict__ filt,
                                                       float* __restrict__ out,
                                                       float K, float U0p) {
    __shared__ float2 tab[NA];         // (cos*K, sin*K)
    __shared__ float  part[256];
    const int t = threadIdx.x;
    for (int a = t; a < NA; a += 256) {
        float ang = (float)M_PI * (float)a / (float)NA;
        float s, c;
        sincosf(ang, &s, &c);
        tab[a] = make_float2(c * K, s * K);
    }
    __syncthreads();

    const int blk  = blockIdx.x;             // [0, 2048)
    const int img  = blk >> 10;              // {0,1}
    const int iy   = (blk >> 2) & 255;       // [0,256)
    const int jx0  = (blk & 3) * 64;         // pixel segment base
    const int lane = t & 63;                 // pixel within segment
    const int wv   = t >> 6;                 // angle chunk [0,4)

    const float xg = -1.f + 2.f * (float)(jx0 + lane) / 255.f;
    const float yg = -1.f + 2.f * (float)iy / 255.f;

    const float* __restrict__ base = filt + (size_t)img * NA * ST;
    float acc = 0.f;
    const int a0 = wv * (NA / 4);            // 90 angles per wave

#pragma unroll 6
    for (int a = a0; a < a0 + NA / 4; ++a) {
        float2 cs = tab[a];
        float u  = fmaf(xg, cs.x, fmaf(yg, cs.y, U0p));
        float uf = floorf(u);                  // u >= 0 always (padded)
        int   i0 = (int)uf;                    // -> v_cvt_flr_i32_f32
        float w  = u - uf;                     // -> v_fract_f32
        const float* rowp = base + a * ST;     // wave-uniform -> saddr form
        float2 tp = *(const float2*)(rowp + i0);  // one dwordx2 gather
        acc = fmaf(w, tp.y - tp.x, acc + tp.x);
    }

    part[t] = acc;
    __syncthreads();

    if (t < 64) {
        float s = part[t] + part[t + 64] + part[t + 128] + part[t + 192];
        out[img * 65536 + iy * 256 + jx0 + t] = s * ((float)M_PI / (float)NA);
    }
}

// ---------------------------------------------------------------------------
extern "C" void kernel_launch(void* const* d_in, const int* in_sizes, int n_in,
                              void* d_out, int out_size, void* d_ws, size_t ws_size,
                              hipStream_t stream) {
    const float* sino = (const float*)d_in[0];   // (2,1,360,363) f32
    float* out = (float*)d_out;                  // (2,1,256,256) f32
    float* filt = (float*)d_ws;                  // 720 * 544 floats = 1.57 MB

    // geometry constants (double, matches reference)
    const double scale = (double)(IMG - 1) / 2.0 * sqrt(2.0) / ((double)(ND - 1) / 2.0);
    const float  K   = (float)(0.5 * (double)(ND - 1) / scale);
    const float  U0p = 0.5f * (float)(ND - 1) + (float)PAD;

    fbp_conv<<<NB * NA, 384, 0, stream>>>(sino, filt);
    fbp_backproj<<<2048, 256, 0, stream>>>(filt, out, K, U0p);
}

// Round 5
// 89.761 us; speedup vs baseline: 2.9141x; 1.0661x over previous
//
#include <hip/hip_runtime.h>
#include <math.h>

#define IMG 256
#define NA  360
#define ND  363
#define NB  2                  // B*C image count
#define KMAX 181               // (ND-1)/2
#define ST  544                // padded row stride for filtered sinogram
#define PAD 76                 // left zero-pad (min u = 181 - 181.7*sqrt(2) > -76)
// reachable padded index range: [0, 514] < ST  (i0 in [-76,437], i1 <= 438)

// ---------------------------------------------------------------------------
// Kernel 1: ramp filter (circular conv) + zero-padded output layout.
// h table per block from the closed form of sum_{k=1}^{K} k*cos(kw):
//   S(w) = ((K+1)cos(Kw) - K*cos((K+1)w) - 1) / (2*(1-cos w)),  S(0)=K(K+1)/2
//   h[n] = S(2*pi*n/ND) * 4/ND^2
// Conv loop pairs m,m-1: per-thread tap addresses ht[x], ht[x+1] are adjacent
// -> backend merges the two ds_read_b32 into ONE ds_read2_b32 (halves LDS
// issue count, the kernel's bottleneck). Dual accumulators for fma ILP.
// Sinogram taps srow[m] are wave-uniform -> scalar loads.
// ---------------------------------------------------------------------------
__global__ __launch_bounds__(384) void fbp_conv(const float* __restrict__ sino,
                                                float* __restrict__ filt) {
    __shared__ float ht[2 * ND - 1];   // ht[i] = h_circ[i - 362], i in [0,725)
    const int row = blockIdx.x;
    const int t = threadIdx.x;

    for (int i = t; i < 2 * ND - 1; i += 384) {
        int n = i - (ND - 1);
        double S;
        if (n == 0) {
            S = (double)KMAX * (double)(KMAX + 1) * 0.5;   // 16471
        } else {
            double w = (2.0 * M_PI / (double)ND) * (double)n;
            S = ((double)(KMAX + 1) * cos((double)KMAX * w)
               - (double)KMAX * cos((double)(KMAX + 1) * w) - 1.0)
              / (2.0 * (1.0 - cos(w)));
        }
        ht[i] = (float)(S * (4.0 / ((double)ND * (double)ND)));
    }
    __syncthreads();

    const float* __restrict__ srow = sino + (size_t)row * ND;
    float* __restrict__ orow = filt + (size_t)row * ST;

    if (t < ND) {
        float acc0 = 0.f, acc1 = 0.f;
        int x = t;                      // tap index for current m (ascending)
#pragma unroll 8
        for (int m = ND - 1; m >= 1; m -= 2) {
            float h0 = ht[x];
            float h1 = ht[x + 1];       // adjacent -> ds_read2_b32 with h0
            acc0 = fmaf(srow[m],     h0, acc0);
            acc1 = fmaf(srow[m - 1], h1, acc1);
            x += 2;
        }
        // leftover m = 0 (363 taps total)
        acc0 = fmaf(srow[0], ht[t + (ND - 1)], acc0 + acc1);
        orow[PAD + t] = acc0;
    }
    // zero pads: [0,PAD) and [PAD+ND, ST)
    if (t < PAD) orow[t] = 0.f;
    if (t >= PAD && t < PAD + (ST - PAD - ND)) orow[PAD + ND + (t - PAD)] = 0.f;
}

// ---------------------------------------------------------------------------
// Kernel 2: backprojection.
//  - 2048 blocks x 256 threads: block covers 64 consecutive pixels of one
//    image row; wave w (= t>>6) handles angles [w*90, w*90+90).
//  - zero-padded filt rows -> unconditional branchless loads; both bilinear
//    taps fetched with ONE float2 gather (global_load_dwordx2).
//  - fused lerp: acc = fma(w, B-A, acc+A).
//  - 4 wave-partials combined in LDS, one coalesced 64-wide store.
//  - __launch_bounds__(256,8): 8 blocks/CU = 32 waves/CU (full occupancy).
// ---------------------------------------------------------------------------
__global__ __launch_bounds__(256, 8) void fbp_backproj(const float* __restrict__ filt,
                                                       float* __restrict__ out,
                                                       float K, float U0p) {
    __shared__ float2 tab[NA];         // (cos*K, sin*K)
    __shared__ float  part[256];
    const int t = threadIdx.x;
    for (int a = t; a < NA; a += 256) {
        float ang = (float)M_PI * (float)a / (float)NA;
        float s, c;
        sincosf(ang, &s, &c);
        tab[a] = make_float2(c * K, s * K);
    }
    __syncthreads();

    const int blk  = blockIdx.x;             // [0, 2048)
    const int img  = blk >> 10;              // {0,1}
    const int iy   = (blk >> 2) & 255;       // [0,256)
    const int jx0  = (blk & 3) * 64;         // pixel segment base
    const int lane = t & 63;                 // pixel within segment
    const int wv   = t >> 6;                 // angle chunk [0,4)

    const float xg = -1.f + 2.f * (float)(jx0 + lane) / 255.f;
    const float yg = -1.f + 2.f * (float)iy / 255.f;

    const float* __restrict__ base = filt + (size_t)img * NA * ST;
    float acc = 0.f;
    const int a0 = wv * (NA / 4);            // 90 angles per wave

#pragma unroll 6
    for (int a = a0; a < a0 + NA / 4; ++a) {
        float2 cs = tab[a];
        float u  = fmaf(xg, cs.x, fmaf(yg, cs.y, U0p));
        float uf = floorf(u);                  // u >= 0 always (padded)
        int   i0 = (int)uf;                    // -> v_cvt_flr_i32_f32
        float w  = u - uf;                     // -> v_fract_f32
        const float* rowp = base + a * ST;     // wave-uniform -> saddr form
        float2 tp = *(const float2*)(rowp + i0);  // one dwordx2 gather
        acc = fmaf(w, tp.y - tp.x, acc + tp.x);
    }

    part[t] = acc;
    __syncthreads();

    if (t < 64) {
        float s = part[t] + part[t + 64] + part[t + 128] + part[t + 192];
        out[img * 65536 + iy * 256 + jx0 + t] = s * ((float)M_PI / (float)NA);
    }
}

// ---------------------------------------------------------------------------
extern "C" void kernel_launch(void* const* d_in, const int* in_sizes, int n_in,
                              void* d_out, int out_size, void* d_ws, size_t ws_size,
                              hipStream_t stream) {
    const float* sino = (const float*)d_in[0];   // (2,1,360,363) f32
    float* out = (float*)d_out;                  // (2,1,256,256) f32
    float* filt = (float*)d_ws;                  // 720 * 544 floats = 1.57 MB

    // geometry constants (double, matches reference)
    const double scale = (double)(IMG - 1) / 2.0 * sqrt(2.0) / ((double)(ND - 1) / 2.0);
    const float  K   = (float)(0.5 * (double)(ND - 1) / scale);
    const float  U0p = 0.5f * (float)(ND - 1) + (float)PAD;

    fbp_conv<<<NB * NA, 384, 0, stream>>>(sino, filt);
    fbp_backproj<<<2048, 256, 0, stream>>>(filt, out, K, U0p);
}